// Round 8
// baseline (71.758 us; speedup 1.0000x reference)
//
#include <hip/hip_runtime.h>

// BiGNN R8: H-precompute (swapped-MFMA, packed stores) + 2-waves-per-tile
// gather (neighbors split k<8/k>=8 per wave, LDS pkmax combine) to double
// wave-level gather concurrency. Final 192->64 MFMA swapped -> f32x4 stores.

typedef __attribute__((ext_vector_type(8))) _Float16 half8;
typedef __attribute__((ext_vector_type(4))) int i32x4;
typedef __attribute__((ext_vector_type(4))) float f32x4;
typedef __attribute__((ext_vector_type(2))) _Float16 h2;

constexpr int N_ROWS = 50000;
constexpr int M1 = 200000, M2 = 100000;
constexpr int C1 = 32, C2 = 64, CL = 64, CG = 64;
constexpr float EPS = 1e-3f;
constexpr int N_TILES = N_ROWS / 16;                 // 3125 (exact)

// ---- workspace layout (bytes) ----
constexpr size_t H2_OFF  = (size_t)M1 * CG * 2;      // 25,600,000
constexpr size_t WOF_OFF = H2_OFF + (size_t)M2 * CG * 2;  // 38,400,000
constexpr size_t STO_OFF = WOF_OFF + 24 * 64 * 16;
constexpr size_t WS_NEED = STO_OFF + 64 * 8;

constexpr int NB1 = (M1 + 63) / 64;                  // 3125
constexpr int NB2 = (M2 + 63) / 64;                  // 1563

__device__ __forceinline__ h2 pkrtz(float a, float b) {
    return (h2)__builtin_amdgcn_cvt_pkrtz(a, b);
}
__device__ __forceinline__ half8 pack8f(f32x4 x, f32x4 y) {
    h2 a = pkrtz(x[0], x[1]), b = pkrtz(x[2], x[3]);
    h2 c = pkrtz(y[0], y[1]), d = pkrtz(y[2], y[3]);
    half8 r;
    r[0]=a[0]; r[1]=a[1]; r[2]=b[0]; r[3]=b[1];
    r[4]=c[0]; r[5]=c[1]; r[6]=d[0]; r[7]=d[1];
    return r;
}
__device__ __forceinline__ int pkmax(int a, int b) {
    int d;
    asm("v_pk_max_f16 %0, %1, %2" : "=v"(d) : "v"(a), "v"(b));
    return d;
}
#define MFMA16(a, b, c) __builtin_amdgcn_mfma_f32_16x16x32_f16((a), (b), (c), 0, 0, 0)

// ---- H = relu(BN(tab @ W)) for one 64-row block; swapped MFMA so each lane
// owns one table row x 4 consecutive channels per nt -> packed 8-B stores.
template<int C>
__device__ __forceinline__ void make_h_body(
    const float* __restrict__ tab, const float* __restrict__ W,
    const float* __restrict__ bn, _Float16* __restrict__ H, int M, int blk)
{
    const int t = threadIdx.x, lane = t & 63, lc = lane & 15, hi = lane >> 4;
    const int wave = t >> 6;
    const int base = blk * 64 + wave * 16;

    half8 bW[C / 32][4];
#pragma unroll
    for (int ck = 0; ck < C / 32; ++ck)
#pragma unroll
        for (int nt = 0; nt < 4; ++nt)
#pragma unroll
            for (int j = 0; j < 8; ++j)
                bW[ck][nt][j] = (_Float16)W[(ck * 32 + hi * 8 + j) * CG + nt * 16 + lc];

    const int rowv = base + lc;
    const int r32  = min(rowv, M - 1);
    f32x4 acc[4] = {{0,0,0,0},{0,0,0,0},{0,0,0,0},{0,0,0,0}};
#pragma unroll
    for (int ck = 0; ck < C / 32; ++ck) {
        const f32x4* gp = (const f32x4*)(tab + (size_t)r32 * C + ck * 32 + hi * 8);
        half8 af = pack8f(gp[0], gp[1]);
#pragma unroll
        for (int nt = 0; nt < 4; ++nt)
            acc[nt] = MFMA16(bW[ck][nt], af, acc[nt]);   // swapped: D[ch][row]
    }
#pragma unroll
    for (int nt = 0; nt < 4; ++nt) {
        const int ch = nt * 16 + hi * 4;                 // 4 consecutive channels
        f32x4 g4 = *(const f32x4*)(bn + ch);
        f32x4 b4 = *(const f32x4*)(bn + 64 + ch);
        f32x4 m4 = *(const f32x4*)(bn + 128 + ch);
        f32x4 v4 = *(const f32x4*)(bn + 192 + ch);
        float v[4];
#pragma unroll
        for (int j = 0; j < 4; ++j) {
            float s = g4[j] * rsqrtf(v4[j] + EPS);
            v[j] = fmaxf(0.f, fmaf(s, acc[nt][j], fmaf(-m4[j], s, b4[j])));
        }
        if (rowv < M) {
            int2 st = { __builtin_bit_cast(int, pkrtz(v[0], v[1])),
                        __builtin_bit_cast(int, pkrtz(v[2], v[3])) };
            *(int2*)(H + (size_t)rowv * CG + ch) = st;
        }
    }
}

__global__ __launch_bounds__(256)
void prep_all(const float* __restrict__ feat_s1, const float* __restrict__ feat_s2,
              const float* __restrict__ Wg1, const float* __restrict__ bn_g1,
              const float* __restrict__ Wg2, const float* __restrict__ bn_g2,
              const float* __restrict__ Wout, const float* __restrict__ bn_out,
              _Float16* __restrict__ H1, _Float16* __restrict__ H2,
              half8* __restrict__ wof, float2* __restrict__ sto)
{
    int blk = blockIdx.x;
    if (blk < NB1) {
        make_h_body<C1>(feat_s1, Wg1, bn_g1, H1, M1, blk);
    } else if (blk < NB1 + NB2) {
        make_h_body<C2>(feat_s2, Wg2, bn_g2, H2, M2, blk - NB1);
    } else {
        for (int g = threadIdx.x; g < 24 * 64 + 64; g += 256) {
            if (g < 24 * 64) {
                int fid = g >> 6, lane = g & 63;
                int ck = fid >> 2, nt = fid & 3, lc = lane & 15, hi = lane >> 4;
                half8 r;
#pragma unroll
                for (int j = 0; j < 8; ++j)
                    r[j] = (_Float16)Wout[(ck * 32 + hi * 8 + j) * CG + nt * 16 + lc];
                wof[g] = r;
            } else {
                int ch = g - 24 * 64;
                float s = bn_out[ch] * rsqrtf(bn_out[192 + ch] + EPS);
                sto[ch] = make_float2(s, fmaf(-bn_out[128 + ch], s, bn_out[64 + ch]));
            }
        }
    }
}

// load 2 neighbors' full H rows (4 x 16B)
#define LB(HT, ia, ib, B)                                                      \
    {                                                                          \
        const _Float16* sa_ = (HT) + (size_t)(unsigned)(ia) * CG + hi * 8;     \
        const _Float16* sb_ = (HT) + (size_t)(unsigned)(ib) * CG + hi * 8;     \
        B[0] = *(const i32x4*)(const void*)sa_;                                \
        B[1] = *(const i32x4*)(const void*)(sa_ + 32);                         \
        B[2] = *(const i32x4*)(const void*)sb_;                                \
        B[3] = *(const i32x4*)(const void*)(sb_ + 32);                         \
    }
#define MB(B, ph0, ph1)                                                        \
    _Pragma("unroll")                                                          \
    for (int c_ = 0; c_ < 4; ++c_) {                                           \
        ph0[c_] = pkmax(ph0[c_], B[0][c_]);                                    \
        ph1[c_] = pkmax(ph1[c_], B[1][c_]);                                    \
        ph0[c_] = pkmax(ph0[c_], B[2][c_]);                                    \
        ph1[c_] = pkmax(ph1[c_], B[3][c_]);                                    \
    }

__global__ __launch_bounds__(256, 6)
void bignn_gather(const _Float16* __restrict__ H1f, const _Float16* __restrict__ H2f,
                  const float* __restrict__ feat_last,
                  const int* __restrict__ idx_s1, const int* __restrict__ idx_s2,
                  const half8* __restrict__ wof, const float2* __restrict__ sto,
                  float* __restrict__ out)
{
    __shared__ i32x4 plds[2][4][64];                  // 8 KB: partner p-frags

    const int t = threadIdx.x, lane = t & 63, lc = lane & 15, hi = lane >> 4;
    const int wave = t >> 6, ti = wave >> 1, half = wave & 1;
    const int tile = blockIdx.x * 2 + ti;
    const bool active = tile < N_TILES;
    const int row = tile * 16 + lc;                   // N_ROWS % 16 == 0

    i32x4 p1h0 = {0,0,0,0}, p1h1 = {0,0,0,0};
    i32x4 p2h0 = {0,0,0,0}, p2h1 = {0,0,0,0};
    f32x4 f0 = {}, f1 = {}, f2 = {}, f3 = {};

    if (active) {
        const size_t ib = (size_t)row * 16 + half * 8;  // this wave's 8 nbrs
        i32x4 I1a = *(const i32x4*)(const void*)(idx_s1 + ib);
        i32x4 I1b = *(const i32x4*)(const void*)(idx_s1 + ib + 4);
        i32x4 b0[4], b1[4], b2[4];
        LB(H1f, I1a[0], I1a[1], b0);
        LB(H1f, I1a[2], I1a[3], b1);
        LB(H1f, I1b[0], I1b[1], b2);
        i32x4 I2a = *(const i32x4*)(const void*)(idx_s2 + ib);
        i32x4 I2b = *(const i32x4*)(const void*)(idx_s2 + ib + 4);
        MB(b0, p1h0, p1h1);
        LB(H1f, I1b[2], I1b[3], b0);
        MB(b1, p1h0, p1h1);
        LB(H2f, I2a[0], I2a[1], b1);
        MB(b2, p1h0, p1h1);
        LB(H2f, I2a[2], I2a[3], b2);
        MB(b0, p1h0, p1h1);
        LB(H2f, I2b[0], I2b[1], b0);
        MB(b1, p2h0, p2h1);
        LB(H2f, I2b[2], I2b[3], b1);
        MB(b2, p2h0, p2h1);
        if (half == 0) {                              // feat_last under gather tail
            const f32x4* flp = (const f32x4*)(feat_last + (size_t)row * CL + hi * 8);
            f0 = flp[0]; f1 = flp[1];
            const f32x4* flq = (const f32x4*)(feat_last + (size_t)row * CL + 32 + hi * 8);
            f2 = flq[0]; f3 = flq[1];
        }
        MB(b0, p2h0, p2h1);
        MB(b1, p2h0, p2h1);
        if (half == 1) {
            plds[ti][0][lane] = p1h0; plds[ti][1][lane] = p1h1;
            plds[ti][2][lane] = p2h0; plds[ti][3][lane] = p2h1;
        }
    }
    __syncthreads();
    if (active && half == 0) {
        i32x4 q0 = plds[ti][0][lane], q1 = plds[ti][1][lane];
        i32x4 q2 = plds[ti][2][lane], q3 = plds[ti][3][lane];
#pragma unroll
        for (int c = 0; c < 4; ++c) {
            p1h0[c] = pkmax(p1h0[c], q0[c]);
            p1h1[c] = pkmax(p1h1[c], q1[c]);
            p2h0[c] = pkmax(p2h0[c], q2[c]);
            p2h1[c] = pkmax(p2h1[c], q3[c]);
        }
        half8 A[6];
        A[0] = pack8f(f0, f1);
        A[1] = pack8f(f2, f3);
        A[2] = __builtin_bit_cast(half8, p1h0);
        A[3] = __builtin_bit_cast(half8, p1h1);
        A[4] = __builtin_bit_cast(half8, p2h0);
        A[5] = __builtin_bit_cast(half8, p2h1);

        f32x4 facc[4] = {{0,0,0,0},{0,0,0,0},{0,0,0,0},{0,0,0,0}};
#pragma unroll
        for (int ck = 0; ck < 6; ++ck)
#pragma unroll
            for (int nt = 0; nt < 4; ++nt)
                facc[nt] = MFMA16(wof[(ck * 4 + nt) * 64 + lane], A[ck], facc[nt]);

        const float* stf = (const float*)sto;
#pragma unroll
        for (int nt = 0; nt < 4; ++nt) {
            const int ch = nt * 16 + hi * 4;
            f32x4 s01 = *(const f32x4*)(stf + ch * 2);      // s0 t0 s1 t1
            f32x4 s23 = *(const f32x4*)(stf + ch * 2 + 4);  // s2 t2 s3 t3
            f32x4 v;
            v[0] = fmaxf(0.f, fmaf(s01[0], facc[nt][0], s01[1]));
            v[1] = fmaxf(0.f, fmaf(s01[2], facc[nt][1], s01[3]));
            v[2] = fmaxf(0.f, fmaf(s23[0], facc[nt][2], s23[1]));
            v[3] = fmaxf(0.f, fmaf(s23[2], facc[nt][3], s23[3]));
            *(f32x4*)(out + (size_t)row * CG + ch) = v;
        }
    }
}

// ---- fallback (ws too small): one block per row, f32, correct but slow ----
__global__ __launch_bounds__(256)
void bignn_ref(const float* __restrict__ feat_s1, const float* __restrict__ feat_s2,
               const float* __restrict__ feat_last,
               const float* __restrict__ Wg1, const float* __restrict__ bn_g1,
               const float* __restrict__ Wg2, const float* __restrict__ bn_g2,
               const float* __restrict__ Wout, const float* __restrict__ bn_out,
               const int* __restrict__ idx_s1, const int* __restrict__ idx_s2,
               float* __restrict__ out)
{
    __shared__ float p[128];
    const int row = blockIdx.x, t = threadIdx.x;
    if (t < 128) {
        const int ch = t & 63;
        const bool g2 = t >= 64;
        const float* bn = g2 ? bn_g2 : bn_g1;
        const float* W  = g2 ? Wg2 : Wg1;
        const float* tab = g2 ? feat_s2 : feat_s1;
        const int*   idx = g2 ? idx_s2 : idx_s1;
        const int C = g2 ? C2 : C1;
        float s = bn[ch] * rsqrtf(bn[192 + ch] + EPS);
        float tt = fmaf(-bn[128 + ch], s, bn[64 + ch]);
        float pv = 0.f;
        for (int k = 0; k < 16; ++k) {
            int nb = idx[(size_t)row * 16 + k];
            float h = 0.f;
            for (int c = 0; c < C; ++c)
                h = fmaf(tab[(size_t)nb * C + c], W[c * CG + ch], h);
            pv = fmaxf(pv, fmaxf(0.f, fmaf(s, h, tt)));
        }
        p[t] = pv;
    }
    __syncthreads();
    if (t < 64) {
        float acc = 0.f;
        for (int j = 0; j < 64; ++j)
            acc = fmaf(feat_last[(size_t)row * CL + j], Wout[j * CG + t], acc);
        for (int j = 0; j < 128; ++j)
            acc = fmaf(p[j], Wout[(64 + j) * CG + t], acc);
        float s = bn_out[t] * rsqrtf(bn_out[192 + t] + EPS);
        float tt = fmaf(-bn_out[128 + t], s, bn_out[64 + t]);
        out[(size_t)row * CG + t] = fmaxf(0.f, fmaf(s, acc, tt));
    }
}

extern "C" void kernel_launch(void* const* d_in, const int* in_sizes, int n_in,
                              void* d_out, int out_size, void* d_ws, size_t ws_size,
                              hipStream_t stream) {
    const float* feat_s1   = (const float*)d_in[0];
    const float* feat_s2   = (const float*)d_in[1];
    const float* feat_last = (const float*)d_in[2];
    const float* Wg1       = (const float*)d_in[3];
    const float* bn_g1     = (const float*)d_in[4];
    const float* Wg2       = (const float*)d_in[5];
    const float* bn_g2     = (const float*)d_in[6];
    const float* Wout      = (const float*)d_in[7];
    const float* bn_out    = (const float*)d_in[8];
    const int*   idx_s1    = (const int*)d_in[9];
    const int*   idx_s2    = (const int*)d_in[10];
    float* out = (float*)d_out;

    if (ws_size >= WS_NEED) {
        _Float16* H1  = (_Float16*)d_ws;
        _Float16* H2  = (_Float16*)((char*)d_ws + H2_OFF);
        half8*    wof = (half8*)((char*)d_ws + WOF_OFF);
        float2*   sto = (float2*)((char*)d_ws + STO_OFF);
        prep_all<<<NB1 + NB2 + 1, 256, 0, stream>>>(
            feat_s1, feat_s2, Wg1, bn_g1, Wg2, bn_g2, Wout, bn_out,
            H1, H2, wof, sto);
        bignn_gather<<<(N_TILES + 1) / 2, 256, 0, stream>>>(
            H1, H2, feat_last, idx_s1, idx_s2, wof, sto, out);
    } else {
        bignn_ref<<<N_ROWS, 256, 0, stream>>>(
            feat_s1, feat_s2, feat_last, Wg1, bn_g1, Wg2, bn_g2, Wout, bn_out,
            idx_s1, idx_s2, out);
    }
}

// Round 9
// 67.707 us; speedup vs baseline: 1.0598x; 1.0598x over previous
//
#include <hip/hip_runtime.h>

// BiGNN R9: deep-pipelined gather (5-slot rotation, ~20 16B-loads in flight
// per wave) + amortized prep (256 rows/block, frags built once per wave,
// 2-deep group pipeline). 1 wave per 16-row tile, no LDS, swapped MFMAs
// everywhere -> packed stores.

typedef __attribute__((ext_vector_type(8))) _Float16 half8;
typedef __attribute__((ext_vector_type(4))) int i32x4;
typedef __attribute__((ext_vector_type(4))) float f32x4;
typedef __attribute__((ext_vector_type(2))) _Float16 h2;

constexpr int N_ROWS = 50000;
constexpr int M1 = 200000, M2 = 100000;
constexpr int C1 = 32, C2 = 64, CL = 64, CG = 64;
constexpr float EPS = 1e-3f;
constexpr int N_TILES = N_ROWS / 16;                 // 3125 (exact)

// ---- workspace layout (bytes) ----
constexpr size_t H2_OFF  = (size_t)M1 * CG * 2;      // 25,600,000
constexpr size_t WOF_OFF = H2_OFF + (size_t)M2 * CG * 2;  // 38,400,000
constexpr size_t STO_OFF = WOF_OFF + 24 * 64 * 16;
constexpr size_t WS_NEED = STO_OFF + 64 * 8;

constexpr int NB1 = (M1 + 255) / 256;                // 782
constexpr int NB2 = (M2 + 255) / 256;                // 391

__device__ __forceinline__ h2 pkrtz(float a, float b) {
    return (h2)__builtin_amdgcn_cvt_pkrtz(a, b);
}
__device__ __forceinline__ half8 pack8f(f32x4 x, f32x4 y) {
    h2 a = pkrtz(x[0], x[1]), b = pkrtz(x[2], x[3]);
    h2 c = pkrtz(y[0], y[1]), d = pkrtz(y[2], y[3]);
    half8 r;
    r[0]=a[0]; r[1]=a[1]; r[2]=b[0]; r[3]=b[1];
    r[4]=c[0]; r[5]=c[1]; r[6]=d[0]; r[7]=d[1];
    return r;
}
__device__ __forceinline__ int pkmax(int a, int b) {
    int d;
    asm("v_pk_max_f16 %0, %1, %2" : "=v"(d) : "v"(a), "v"(b));
    return d;
}
#define MFMA16(a, b, c) __builtin_amdgcn_mfma_f32_16x16x32_f16((a), (b), (c), 0, 0, 0)

// ---- prep: H = relu(BN(tab @ W)), 256 rows/block, 64/wave in 4 groups ----
template<int C>
__device__ __forceinline__ void make_h_multi(
    const float* __restrict__ tab, const float* __restrict__ W,
    const float* __restrict__ bn, _Float16* __restrict__ H, int M, int blk)
{
    const int t = threadIdx.x, lane = t & 63, lc = lane & 15, hi = lane >> 4;
    const int wave = t >> 6;
    const int wbase = blk * 256 + wave * 64;
    constexpr int CK = C / 32;

    half8 bW[CK][4];
#pragma unroll
    for (int ck = 0; ck < CK; ++ck)
#pragma unroll
        for (int nt = 0; nt < 4; ++nt)
#pragma unroll
            for (int j = 0; j < 8; ++j)
                bW[ck][nt][j] = (_Float16)W[(ck * 32 + hi * 8 + j) * CG + nt * 16 + lc];

    f32x4 s4[4], t4[4];
#pragma unroll
    for (int nt = 0; nt < 4; ++nt) {
        const int ch = nt * 16 + hi * 4;
        f32x4 g4 = *(const f32x4*)(bn + ch);
        f32x4 b4 = *(const f32x4*)(bn + 64 + ch);
        f32x4 m4 = *(const f32x4*)(bn + 128 + ch);
        f32x4 v4 = *(const f32x4*)(bn + 192 + ch);
#pragma unroll
        for (int j = 0; j < 4; ++j) {
            float s = g4[j] * rsqrtf(v4[j] + EPS);
            s4[nt][j] = s;
            t4[nt][j] = fmaf(-m4[j], s, b4[j]);
        }
    }

    f32x4 raw[2][CK][2];                              // 2-deep group pipeline
    {
        const int r = min(wbase + lc, M - 1);
#pragma unroll
        for (int ck = 0; ck < CK; ++ck) {
            const f32x4* gp = (const f32x4*)(tab + (size_t)r * C + ck * 32 + hi * 8);
            raw[0][ck][0] = gp[0]; raw[0][ck][1] = gp[1];
        }
    }
#pragma unroll
    for (int g = 0; g < 4; ++g) {
        if (g < 3) {
            const int rn = min(wbase + (g + 1) * 16 + lc, M - 1);
#pragma unroll
            for (int ck = 0; ck < CK; ++ck) {
                const f32x4* gp = (const f32x4*)(tab + (size_t)rn * C + ck * 32 + hi * 8);
                raw[(g + 1) & 1][ck][0] = gp[0]; raw[(g + 1) & 1][ck][1] = gp[1];
            }
        }
        f32x4 acc[4] = {{0,0,0,0},{0,0,0,0},{0,0,0,0},{0,0,0,0}};
#pragma unroll
        for (int ck = 0; ck < CK; ++ck) {
            half8 af = pack8f(raw[g & 1][ck][0], raw[g & 1][ck][1]);
#pragma unroll
            for (int nt = 0; nt < 4; ++nt)
                acc[nt] = MFMA16(bW[ck][nt], af, acc[nt]);   // D[ch][row]
        }
        const int rowv = wbase + g * 16 + lc;
        if (rowv < M) {
#pragma unroll
            for (int nt = 0; nt < 4; ++nt) {
                float v0 = fmaxf(0.f, fmaf(s4[nt][0], acc[nt][0], t4[nt][0]));
                float v1 = fmaxf(0.f, fmaf(s4[nt][1], acc[nt][1], t4[nt][1]));
                float v2 = fmaxf(0.f, fmaf(s4[nt][2], acc[nt][2], t4[nt][2]));
                float v3 = fmaxf(0.f, fmaf(s4[nt][3], acc[nt][3], t4[nt][3]));
                int2 stv = { __builtin_bit_cast(int, pkrtz(v0, v1)),
                             __builtin_bit_cast(int, pkrtz(v2, v3)) };
                *(int2*)(H + (size_t)rowv * CG + nt * 16 + hi * 4) = stv;
            }
        }
    }
}

__global__ __launch_bounds__(256, 3)
void prep_all(const float* __restrict__ feat_s1, const float* __restrict__ feat_s2,
              const float* __restrict__ Wg1, const float* __restrict__ bn_g1,
              const float* __restrict__ Wg2, const float* __restrict__ bn_g2,
              const float* __restrict__ Wout, const float* __restrict__ bn_out,
              _Float16* __restrict__ H1, _Float16* __restrict__ H2,
              half8* __restrict__ wof, float2* __restrict__ sto)
{
    int blk = blockIdx.x;
    if (blk < NB1) {
        make_h_multi<C1>(feat_s1, Wg1, bn_g1, H1, M1, blk);
    } else if (blk < NB1 + NB2) {
        make_h_multi<C2>(feat_s2, Wg2, bn_g2, H2, M2, blk - NB1);
    } else {
        for (int g = threadIdx.x; g < 24 * 64 + 64; g += 256) {
            if (g < 24 * 64) {
                int fid = g >> 6, lane = g & 63;
                int ck = fid >> 2, nt = fid & 3, lc = lane & 15, hi = lane >> 4;
                half8 r;
#pragma unroll
                for (int j = 0; j < 8; ++j)
                    r[j] = (_Float16)Wout[(ck * 32 + hi * 8 + j) * CG + nt * 16 + lc];
                wof[g] = r;
            } else {
                int ch = g - 24 * 64;
                float s = bn_out[ch] * rsqrtf(bn_out[192 + ch] + EPS);
                sto[ch] = make_float2(s, fmaf(-bn_out[128 + ch], s, bn_out[64 + ch]));
            }
        }
    }
}

// ---- gather: 5-slot rotation, 2 neighbors (4 x 16B loads) per slot ----
struct Slot { i32x4 a, b, c, d; };

#define LB2(S, HT, iA, iB) {                                                   \
    const _Float16* pa_ = (HT) + (size_t)(unsigned)(iA) * CG + hi * 8;         \
    const _Float16* pb_ = (HT) + (size_t)(unsigned)(iB) * CG + hi * 8;         \
    S.a = *(const i32x4*)(const void*)pa_;                                     \
    S.b = *(const i32x4*)(const void*)(pa_ + 32);                              \
    S.c = *(const i32x4*)(const void*)pb_;                                     \
    S.d = *(const i32x4*)(const void*)(pb_ + 32); }

#define MXS(S, h0, h1)                                                         \
    _Pragma("unroll")                                                          \
    for (int c_ = 0; c_ < 4; ++c_) {                                           \
        h0[c_] = pkmax(h0[c_], S.a[c_]); h1[c_] = pkmax(h1[c_], S.b[c_]);      \
        h0[c_] = pkmax(h0[c_], S.c[c_]); h1[c_] = pkmax(h1[c_], S.d[c_]);      \
    }

__global__ __launch_bounds__(256, 3)
void bignn_gather(const _Float16* __restrict__ H1f, const _Float16* __restrict__ H2f,
                  const float* __restrict__ feat_last,
                  const int* __restrict__ idx_s1, const int* __restrict__ idx_s2,
                  const half8* __restrict__ wof, const float2* __restrict__ sto,
                  float* __restrict__ out)
{
    const int t = threadIdx.x, lane = t & 63, lc = lane & 15, hi = lane >> 4;
    const int wave = t >> 6;
    const int tile = blockIdx.x * 4 + wave;
    if (tile >= N_TILES) return;
    const int row = tile * 16 + lc;                   // N_ROWS % 16 == 0

    const int* ip1 = idx_s1 + (size_t)row * 16;
    i32x4 I1a = *(const i32x4*)(const void*)(ip1);
    i32x4 I1b = *(const i32x4*)(const void*)(ip1 + 4);
    i32x4 I1c = *(const i32x4*)(const void*)(ip1 + 8);
    i32x4 I1d = *(const i32x4*)(const void*)(ip1 + 12);

    Slot S0, S1, S2, S3, S4;
    LB2(S0, H1f, I1a[0], I1a[1]);
    LB2(S1, H1f, I1a[2], I1a[3]);
    LB2(S2, H1f, I1b[0], I1b[1]);
    LB2(S3, H1f, I1b[2], I1b[3]);
    LB2(S4, H1f, I1c[0], I1c[1]);

    const int* ip2 = idx_s2 + (size_t)row * 16;
    i32x4 I2a = *(const i32x4*)(const void*)(ip2);
    i32x4 I2b = *(const i32x4*)(const void*)(ip2 + 4);
    i32x4 I2c = *(const i32x4*)(const void*)(ip2 + 8);
    i32x4 I2d = *(const i32x4*)(const void*)(ip2 + 12);

    i32x4 p1h0 = {0,0,0,0}, p1h1 = {0,0,0,0};
    i32x4 p2h0 = {0,0,0,0}, p2h1 = {0,0,0,0};

    MXS(S0, p1h0, p1h1); LB2(S0, H1f, I1c[2], I1c[3]);
    MXS(S1, p1h0, p1h1); LB2(S1, H1f, I1d[0], I1d[1]);
    MXS(S2, p1h0, p1h1); LB2(S2, H1f, I1d[2], I1d[3]);
    MXS(S3, p1h0, p1h1); LB2(S3, H2f, I2a[0], I2a[1]);
    MXS(S4, p1h0, p1h1); LB2(S4, H2f, I2a[2], I2a[3]);
    MXS(S0, p1h0, p1h1); LB2(S0, H2f, I2b[0], I2b[1]);
    MXS(S1, p1h0, p1h1); LB2(S1, H2f, I2b[2], I2b[3]);
    MXS(S2, p1h0, p1h1); LB2(S2, H2f, I2c[0], I2c[1]);
    MXS(S3, p2h0, p2h1); LB2(S3, H2f, I2c[2], I2c[3]);
    MXS(S4, p2h0, p2h1); LB2(S4, H2f, I2d[0], I2d[1]);
    // feat_last issued under the T2 consumption tail
    const f32x4* flp = (const f32x4*)(feat_last + (size_t)row * CL + hi * 8);
    f32x4 f0 = flp[0], f1 = flp[1];
    const f32x4* flq = (const f32x4*)(feat_last + (size_t)row * CL + 32 + hi * 8);
    f32x4 f2 = flq[0], f3 = flq[1];
    MXS(S0, p2h0, p2h1); LB2(S0, H2f, I2d[2], I2d[3]);
    MXS(S1, p2h0, p2h1);
    MXS(S2, p2h0, p2h1);
    MXS(S3, p2h0, p2h1);
    MXS(S4, p2h0, p2h1);
    MXS(S0, p2h0, p2h1);

    // final layer: A = [feat_last | p1 | p2], swapped MFMA -> f32x4 stores
    half8 A[6];
    A[0] = pack8f(f0, f1);
    A[1] = pack8f(f2, f3);
    A[2] = __builtin_bit_cast(half8, p1h0);
    A[3] = __builtin_bit_cast(half8, p1h1);
    A[4] = __builtin_bit_cast(half8, p2h0);
    A[5] = __builtin_bit_cast(half8, p2h1);

    f32x4 facc[4] = {{0,0,0,0},{0,0,0,0},{0,0,0,0},{0,0,0,0}};
#pragma unroll
    for (int ck = 0; ck < 6; ++ck)
#pragma unroll
        for (int nt = 0; nt < 4; ++nt)
            facc[nt] = MFMA16(wof[(ck * 4 + nt) * 64 + lane], A[ck], facc[nt]);

    const float* stf = (const float*)sto;
#pragma unroll
    for (int nt = 0; nt < 4; ++nt) {
        const int ch = nt * 16 + hi * 4;
        f32x4 s01 = *(const f32x4*)(stf + ch * 2);      // s0 t0 s1 t1
        f32x4 s23 = *(const f32x4*)(stf + ch * 2 + 4);  // s2 t2 s3 t3
        f32x4 v;
        v[0] = fmaxf(0.f, fmaf(s01[0], facc[nt][0], s01[1]));
        v[1] = fmaxf(0.f, fmaf(s01[2], facc[nt][1], s01[3]));
        v[2] = fmaxf(0.f, fmaf(s23[0], facc[nt][2], s23[1]));
        v[3] = fmaxf(0.f, fmaf(s23[2], facc[nt][3], s23[3]));
        *(f32x4*)(out + (size_t)row * CG + ch) = v;
    }
}

// ---- fallback (ws too small): one block per row, f32, correct but slow ----
__global__ __launch_bounds__(256)
void bignn_ref(const float* __restrict__ feat_s1, const float* __restrict__ feat_s2,
               const float* __restrict__ feat_last,
               const float* __restrict__ Wg1, const float* __restrict__ bn_g1,
               const float* __restrict__ Wg2, const float* __restrict__ bn_g2,
               const float* __restrict__ Wout, const float* __restrict__ bn_out,
               const int* __restrict__ idx_s1, const int* __restrict__ idx_s2,
               float* __restrict__ out)
{
    __shared__ float p[128];
    const int row = blockIdx.x, t = threadIdx.x;
    if (t < 128) {
        const int ch = t & 63;
        const bool g2 = t >= 64;
        const float* bn = g2 ? bn_g2 : bn_g1;
        const float* W  = g2 ? Wg2 : Wg1;
        const float* tab = g2 ? feat_s2 : feat_s1;
        const int*   idx = g2 ? idx_s2 : idx_s1;
        const int C = g2 ? C2 : C1;
        float s = bn[ch] * rsqrtf(bn[192 + ch] + EPS);
        float tt = fmaf(-bn[128 + ch], s, bn[64 + ch]);
        float pv = 0.f;
        for (int k = 0; k < 16; ++k) {
            int nb = idx[(size_t)row * 16 + k];
            float h = 0.f;
            for (int c = 0; c < C; ++c)
                h = fmaf(tab[(size_t)nb * C + c], W[c * CG + ch], h);
            pv = fmaxf(pv, fmaxf(0.f, fmaf(s, h, tt)));
        }
        p[t] = pv;
    }
    __syncthreads();
    if (t < 64) {
        float acc = 0.f;
        for (int j = 0; j < 64; ++j)
            acc = fmaf(feat_last[(size_t)row * CL + j], Wout[j * CG + t], acc);
        for (int j = 0; j < 128; ++j)
            acc = fmaf(p[j], Wout[(64 + j) * CG + t], acc);
        float s = bn_out[t] * rsqrtf(bn_out[192 + t] + EPS);
        float tt = fmaf(-bn_out[128 + t], s, bn_out[64 + t]);
        out[(size_t)row * CG + t] = fmaxf(0.f, fmaf(s, acc, tt));
    }
}

extern "C" void kernel_launch(void* const* d_in, const int* in_sizes, int n_in,
                              void* d_out, int out_size, void* d_ws, size_t ws_size,
                              hipStream_t stream) {
    const float* feat_s1   = (const float*)d_in[0];
    const float* feat_s2   = (const float*)d_in[1];
    const float* feat_last = (const float*)d_in[2];
    const float* Wg1       = (const float*)d_in[3];
    const float* bn_g1     = (const float*)d_in[4];
    const float* Wg2       = (const float*)d_in[5];
    const float* bn_g2     = (const float*)d_in[6];
    const float* Wout      = (const float*)d_in[7];
    const float* bn_out    = (const float*)d_in[8];
    const int*   idx_s1    = (const int*)d_in[9];
    const int*   idx_s2    = (const int*)d_in[10];
    float* out = (float*)d_out;

    if (ws_size >= WS_NEED) {
        _Float16* H1  = (_Float16*)d_ws;
        _Float16* H2  = (_Float16*)((char*)d_ws + H2_OFF);
        half8*    wof = (half8*)((char*)d_ws + WOF_OFF);
        float2*   sto = (float2*)((char*)d_ws + STO_OFF);
        prep_all<<<NB1 + NB2 + 1, 256, 0, stream>>>(
            feat_s1, feat_s2, Wg1, bn_g1, Wg2, bn_g2, Wout, bn_out,
            H1, H2, wof, sto);
        bignn_gather<<<(N_TILES + 3) / 4, 256, 0, stream>>>(
            H1, H2, feat_last, idx_s1, idx_s2, wof, sto, out);
    } else {
        bignn_ref<<<N_ROWS, 256, 0, stream>>>(
            feat_s1, feat_s2, feat_last, Wg1, bn_g1, Wg2, bn_g2, Wout, bn_out,
            idx_s1, idx_s2, out);
    }
}

// Round 10
// 66.788 us; speedup vs baseline: 1.0744x; 1.0138x over previous
//
#include <hip/hip_runtime.h>

// BiGNN R10: R9 structure + FORCED load pipeline in the gather kernel.
// 8 named slots, steady 16 loads in flight per wave, program order pinned
// with __builtin_amdgcn_sched_barrier(0) after every issue step so the
// compiler cannot sink loads to their uses (R9 failure mode: VGPR=64 proved
// it serialized the rotation). launch_bounds(256,3) gives the VGPR headroom.

typedef __attribute__((ext_vector_type(8))) _Float16 half8;
typedef __attribute__((ext_vector_type(4))) int i32x4;
typedef __attribute__((ext_vector_type(4))) float f32x4;
typedef __attribute__((ext_vector_type(2))) _Float16 h2;

constexpr int N_ROWS = 50000;
constexpr int M1 = 200000, M2 = 100000;
constexpr int C1 = 32, C2 = 64, CL = 64, CG = 64;
constexpr float EPS = 1e-3f;
constexpr int N_TILES = N_ROWS / 16;                 // 3125 (exact)

// ---- workspace layout (bytes) ----
constexpr size_t H2_OFF  = (size_t)M1 * CG * 2;      // 25,600,000
constexpr size_t WOF_OFF = H2_OFF + (size_t)M2 * CG * 2;  // 38,400,000
constexpr size_t STO_OFF = WOF_OFF + 24 * 64 * 16;
constexpr size_t WS_NEED = STO_OFF + 64 * 8;

constexpr int NB1 = (M1 + 255) / 256;                // 782
constexpr int NB2 = (M2 + 255) / 256;                // 391

__device__ __forceinline__ h2 pkrtz(float a, float b) {
    return (h2)__builtin_amdgcn_cvt_pkrtz(a, b);
}
__device__ __forceinline__ half8 pack8f(f32x4 x, f32x4 y) {
    h2 a = pkrtz(x[0], x[1]), b = pkrtz(x[2], x[3]);
    h2 c = pkrtz(y[0], y[1]), d = pkrtz(y[2], y[3]);
    half8 r;
    r[0]=a[0]; r[1]=a[1]; r[2]=b[0]; r[3]=b[1];
    r[4]=c[0]; r[5]=c[1]; r[6]=d[0]; r[7]=d[1];
    return r;
}
__device__ __forceinline__ int pkmax(int a, int b) {
    int d;
    asm("v_pk_max_f16 %0, %1, %2" : "=v"(d) : "v"(a), "v"(b));
    return d;
}
#define MFMA16(a, b, c) __builtin_amdgcn_mfma_f32_16x16x32_f16((a), (b), (c), 0, 0, 0)
#define SBAR() __builtin_amdgcn_sched_barrier(0)

// ---- prep: H = relu(BN(tab @ W)), 256 rows/block, 64/wave in 4 groups ----
template<int C>
__device__ __forceinline__ void make_h_multi(
    const float* __restrict__ tab, const float* __restrict__ W,
    const float* __restrict__ bn, _Float16* __restrict__ H, int M, int blk)
{
    const int t = threadIdx.x, lane = t & 63, lc = lane & 15, hi = lane >> 4;
    const int wave = t >> 6;
    const int wbase = blk * 256 + wave * 64;
    constexpr int CK = C / 32;

    half8 bW[CK][4];
#pragma unroll
    for (int ck = 0; ck < CK; ++ck)
#pragma unroll
        for (int nt = 0; nt < 4; ++nt)
#pragma unroll
            for (int j = 0; j < 8; ++j)
                bW[ck][nt][j] = (_Float16)W[(ck * 32 + hi * 8 + j) * CG + nt * 16 + lc];

    f32x4 s4[4], t4[4];
#pragma unroll
    for (int nt = 0; nt < 4; ++nt) {
        const int ch = nt * 16 + hi * 4;
        f32x4 g4 = *(const f32x4*)(bn + ch);
        f32x4 b4 = *(const f32x4*)(bn + 64 + ch);
        f32x4 m4 = *(const f32x4*)(bn + 128 + ch);
        f32x4 v4 = *(const f32x4*)(bn + 192 + ch);
#pragma unroll
        for (int j = 0; j < 4; ++j) {
            float s = g4[j] * rsqrtf(v4[j] + EPS);
            s4[nt][j] = s;
            t4[nt][j] = fmaf(-m4[j], s, b4[j]);
        }
    }

    f32x4 raw[2][CK][2];                              // 2-deep group pipeline
    {
        const int r = min(wbase + lc, M - 1);
#pragma unroll
        for (int ck = 0; ck < CK; ++ck) {
            const f32x4* gp = (const f32x4*)(tab + (size_t)r * C + ck * 32 + hi * 8);
            raw[0][ck][0] = gp[0]; raw[0][ck][1] = gp[1];
        }
    }
#pragma unroll
    for (int g = 0; g < 4; ++g) {
        if (g < 3) {
            const int rn = min(wbase + (g + 1) * 16 + lc, M - 1);
#pragma unroll
            for (int ck = 0; ck < CK; ++ck) {
                const f32x4* gp = (const f32x4*)(tab + (size_t)rn * C + ck * 32 + hi * 8);
                raw[(g + 1) & 1][ck][0] = gp[0]; raw[(g + 1) & 1][ck][1] = gp[1];
            }
        }
        f32x4 acc[4] = {{0,0,0,0},{0,0,0,0},{0,0,0,0},{0,0,0,0}};
#pragma unroll
        for (int ck = 0; ck < CK; ++ck) {
            half8 af = pack8f(raw[g & 1][ck][0], raw[g & 1][ck][1]);
#pragma unroll
            for (int nt = 0; nt < 4; ++nt)
                acc[nt] = MFMA16(bW[ck][nt], af, acc[nt]);   // D[ch][row]
        }
        const int rowv = wbase + g * 16 + lc;
        if (rowv < M) {
#pragma unroll
            for (int nt = 0; nt < 4; ++nt) {
                float v0 = fmaxf(0.f, fmaf(s4[nt][0], acc[nt][0], t4[nt][0]));
                float v1 = fmaxf(0.f, fmaf(s4[nt][1], acc[nt][1], t4[nt][1]));
                float v2 = fmaxf(0.f, fmaf(s4[nt][2], acc[nt][2], t4[nt][2]));
                float v3 = fmaxf(0.f, fmaf(s4[nt][3], acc[nt][3], t4[nt][3]));
                int2 stv = { __builtin_bit_cast(int, pkrtz(v0, v1)),
                             __builtin_bit_cast(int, pkrtz(v2, v3)) };
                *(int2*)(H + (size_t)rowv * CG + nt * 16 + hi * 4) = stv;
            }
        }
    }
}

__global__ __launch_bounds__(256, 3)
void prep_all(const float* __restrict__ feat_s1, const float* __restrict__ feat_s2,
              const float* __restrict__ Wg1, const float* __restrict__ bn_g1,
              const float* __restrict__ Wg2, const float* __restrict__ bn_g2,
              const float* __restrict__ Wout, const float* __restrict__ bn_out,
              _Float16* __restrict__ H1, _Float16* __restrict__ H2,
              half8* __restrict__ wof, float2* __restrict__ sto)
{
    int blk = blockIdx.x;
    if (blk < NB1) {
        make_h_multi<C1>(feat_s1, Wg1, bn_g1, H1, M1, blk);
    } else if (blk < NB1 + NB2) {
        make_h_multi<C2>(feat_s2, Wg2, bn_g2, H2, M2, blk - NB1);
    } else {
        for (int g = threadIdx.x; g < 24 * 64 + 64; g += 256) {
            if (g < 24 * 64) {
                int fid = g >> 6, lane = g & 63;
                int ck = fid >> 2, nt = fid & 3, lc = lane & 15, hi = lane >> 4;
                half8 r;
#pragma unroll
                for (int j = 0; j < 8; ++j)
                    r[j] = (_Float16)Wout[(ck * 32 + hi * 8 + j) * CG + nt * 16 + lc];
                wof[g] = r;
            } else {
                int ch = g - 24 * 64;
                float s = bn_out[ch] * rsqrtf(bn_out[192 + ch] + EPS);
                sto[ch] = make_float2(s, fmaf(-bn_out[128 + ch], s, bn_out[64 + ch]));
            }
        }
    }
}

// ---- gather kernel: 8 named slots, 16 loads in flight, pinned schedule ----
// issue one neighbor row (2 x 16B) into slot S
#define ISS(S, HT, idx) {                                                      \
    const _Float16* p_ = (HT) + (size_t)(unsigned)(idx) * CG + hi * 8;         \
    S##a = *(const i32x4*)(const void*)p_;                                     \
    S##b = *(const i32x4*)(const void*)(p_ + 32); }
// consume slot S into (h0,h1)
#define CONS(S, h0, h1)                                                        \
    _Pragma("unroll")                                                          \
    for (int c_ = 0; c_ < 4; ++c_) {                                           \
        h0[c_] = pkmax(h0[c_], S##a[c_]);                                      \
        h1[c_] = pkmax(h1[c_], S##b[c_]);                                      \
    }
// steady-state step: consume S, refill S with row idx from HT, fence order
#define STEP(S, h0, h1, HT, idx)                                               \
    CONS(S, h0, h1); ISS(S, HT, idx); SBAR();

__global__ __launch_bounds__(256, 3)
void bignn_gather(const _Float16* __restrict__ H1f, const _Float16* __restrict__ H2f,
                  const float* __restrict__ feat_last,
                  const int* __restrict__ idx_s1, const int* __restrict__ idx_s2,
                  const half8* __restrict__ wof, const float2* __restrict__ sto,
                  float* __restrict__ out)
{
    const int t = threadIdx.x, lane = t & 63, lc = lane & 15, hi = lane >> 4;
    const int wave = t >> 6;
    const int tile = blockIdx.x * 4 + wave;
    if (tile >= N_TILES) return;
    const int row = tile * 16 + lc;                   // N_ROWS % 16 == 0

    const int* ip1 = idx_s1 + (size_t)row * 16;
    i32x4 I1a = *(const i32x4*)(const void*)(ip1);
    i32x4 I1b = *(const i32x4*)(const void*)(ip1 + 4);
    i32x4 I1c = *(const i32x4*)(const void*)(ip1 + 8);
    i32x4 I1d = *(const i32x4*)(const void*)(ip1 + 12);
    const int* ip2 = idx_s2 + (size_t)row * 16;
    i32x4 I2a = *(const i32x4*)(const void*)(ip2);
    i32x4 I2b = *(const i32x4*)(const void*)(ip2 + 4);
    i32x4 I2c = *(const i32x4*)(const void*)(ip2 + 8);
    i32x4 I2d = *(const i32x4*)(const void*)(ip2 + 12);

    i32x4 S0a, S0b, S1a, S1b, S2a, S2b, S3a, S3b;
    i32x4 S4a, S4b, S5a, S5b, S6a, S6b, S7a, S7b;

    // prologue: fill all 8 slots (16 loads outstanding)
    ISS(S0, H1f, I1a[0]); ISS(S1, H1f, I1a[1]);
    ISS(S2, H1f, I1a[2]); ISS(S3, H1f, I1a[3]);
    ISS(S4, H1f, I1b[0]); ISS(S5, H1f, I1b[1]);
    ISS(S6, H1f, I1b[2]); ISS(S7, H1f, I1b[3]);
    SBAR();

    i32x4 p1h0 = {0,0,0,0}, p1h1 = {0,0,0,0};
    i32x4 p2h0 = {0,0,0,0}, p2h1 = {0,0,0,0};

    // steady state: consume oldest, refill, fence (vmcnt(14) at each CONS)
    STEP(S0, p1h0, p1h1, H1f, I1c[0]);
    STEP(S1, p1h0, p1h1, H1f, I1c[1]);
    STEP(S2, p1h0, p1h1, H1f, I1c[2]);
    STEP(S3, p1h0, p1h1, H1f, I1c[3]);
    STEP(S4, p1h0, p1h1, H1f, I1d[0]);
    STEP(S5, p1h0, p1h1, H1f, I1d[1]);
    STEP(S6, p1h0, p1h1, H1f, I1d[2]);
    STEP(S7, p1h0, p1h1, H1f, I1d[3]);
    STEP(S0, p1h0, p1h1, H2f, I2a[0]);
    STEP(S1, p1h0, p1h1, H2f, I2a[1]);
    STEP(S2, p1h0, p1h1, H2f, I2a[2]);
    STEP(S3, p1h0, p1h1, H2f, I2a[3]);
    STEP(S4, p1h0, p1h1, H2f, I2b[0]);
    STEP(S5, p1h0, p1h1, H2f, I2b[1]);
    STEP(S6, p1h0, p1h1, H2f, I2b[2]);
    STEP(S7, p1h0, p1h1, H2f, I2b[3]);
    STEP(S0, p2h0, p2h1, H2f, I2c[0]);
    STEP(S1, p2h0, p2h1, H2f, I2c[1]);
    STEP(S2, p2h0, p2h1, H2f, I2c[2]);
    STEP(S3, p2h0, p2h1, H2f, I2c[3]);
    STEP(S4, p2h0, p2h1, H2f, I2d[0]);
    STEP(S5, p2h0, p2h1, H2f, I2d[1]);
    STEP(S6, p2h0, p2h1, H2f, I2d[2]);
    STEP(S7, p2h0, p2h1, H2f, I2d[3]);

    // epilogue: feat_last loads overlap the drain of the last 8 slots
    const f32x4* flp = (const f32x4*)(feat_last + (size_t)row * CL + hi * 8);
    f32x4 f0 = flp[0], f1 = flp[1];
    const f32x4* flq = (const f32x4*)(feat_last + (size_t)row * CL + 32 + hi * 8);
    f32x4 f2 = flq[0], f3 = flq[1];
    SBAR();
    CONS(S0, p2h0, p2h1); CONS(S1, p2h0, p2h1);
    CONS(S2, p2h0, p2h1); CONS(S3, p2h0, p2h1);
    CONS(S4, p2h0, p2h1); CONS(S5, p2h0, p2h1);
    CONS(S6, p2h0, p2h1); CONS(S7, p2h0, p2h1);

    // final layer: A = [feat_last | p1 | p2], swapped MFMA -> f32x4 stores
    half8 A[6];
    A[0] = pack8f(f0, f1);
    A[1] = pack8f(f2, f3);
    A[2] = __builtin_bit_cast(half8, p1h0);
    A[3] = __builtin_bit_cast(half8, p1h1);
    A[4] = __builtin_bit_cast(half8, p2h0);
    A[5] = __builtin_bit_cast(half8, p2h1);

    f32x4 facc[4] = {{0,0,0,0},{0,0,0,0},{0,0,0,0},{0,0,0,0}};
#pragma unroll
    for (int ck = 0; ck < 6; ++ck)
#pragma unroll
        for (int nt = 0; nt < 4; ++nt)
            facc[nt] = MFMA16(wof[(ck * 4 + nt) * 64 + lane], A[ck], facc[nt]);

    const float* stf = (const float*)sto;
#pragma unroll
    for (int nt = 0; nt < 4; ++nt) {
        const int ch = nt * 16 + hi * 4;
        f32x4 s01 = *(const f32x4*)(stf + ch * 2);      // s0 t0 s1 t1
        f32x4 s23 = *(const f32x4*)(stf + ch * 2 + 4);  // s2 t2 s3 t3
        f32x4 v;
        v[0] = fmaxf(0.f, fmaf(s01[0], facc[nt][0], s01[1]));
        v[1] = fmaxf(0.f, fmaf(s01[2], facc[nt][1], s01[3]));
        v[2] = fmaxf(0.f, fmaf(s23[0], facc[nt][2], s23[1]));
        v[3] = fmaxf(0.f, fmaf(s23[2], facc[nt][3], s23[3]));
        *(f32x4*)(out + (size_t)row * CG + ch) = v;
    }
}

// ---- fallback (ws too small): one block per row, f32, correct but slow ----
__global__ __launch_bounds__(256)
void bignn_ref(const float* __restrict__ feat_s1, const float* __restrict__ feat_s2,
               const float* __restrict__ feat_last,
               const float* __restrict__ Wg1, const float* __restrict__ bn_g1,
               const float* __restrict__ Wg2, const float* __restrict__ bn_g2,
               const float* __restrict__ Wout, const float* __restrict__ bn_out,
               const int* __restrict__ idx_s1, const int* __restrict__ idx_s2,
               float* __restrict__ out)
{
    __shared__ float p[128];
    const int row = blockIdx.x, t = threadIdx.x;
    if (t < 128) {
        const int ch = t & 63;
        const bool g2 = t >= 64;
        const float* bn = g2 ? bn_g2 : bn_g1;
        const float* W  = g2 ? Wg2 : Wg1;
        const float* tab = g2 ? feat_s2 : feat_s1;
        const int*   idx = g2 ? idx_s2 : idx_s1;
        const int C = g2 ? C2 : C1;
        float s = bn[ch] * rsqrtf(bn[192 + ch] + EPS);
        float tt = fmaf(-bn[128 + ch], s, bn[64 + ch]);
        float pv = 0.f;
        for (int k = 0; k < 16; ++k) {
            int nb = idx[(size_t)row * 16 + k];
            float h = 0.f;
            for (int c = 0; c < C; ++c)
                h = fmaf(tab[(size_t)nb * C + c], W[c * CG + ch], h);
            pv = fmaxf(pv, fmaxf(0.f, fmaf(s, h, tt)));
        }
        p[t] = pv;
    }
    __syncthreads();
    if (t < 64) {
        float acc = 0.f;
        for (int j = 0; j < 64; ++j)
            acc = fmaf(feat_last[(size_t)row * CL + j], Wout[j * CG + t], acc);
        for (int j = 0; j < 128; ++j)
            acc = fmaf(p[j], Wout[(64 + j) * CG + t], acc);
        float s = bn_out[t] * rsqrtf(bn_out[192 + t] + EPS);
        float tt = fmaf(-bn_out[128 + t], s, bn_out[64 + t]);
        out[(size_t)row * CG + t] = fmaxf(0.f, fmaf(s, acc, tt));
    }
}

extern "C" void kernel_launch(void* const* d_in, const int* in_sizes, int n_in,
                              void* d_out, int out_size, void* d_ws, size_t ws_size,
                              hipStream_t stream) {
    const float* feat_s1   = (const float*)d_in[0];
    const float* feat_s2   = (const float*)d_in[1];
    const float* feat_last = (const float*)d_in[2];
    const float* Wg1       = (const float*)d_in[3];
    const float* bn_g1     = (const float*)d_in[4];
    const float* Wg2       = (const float*)d_in[5];
    const float* bn_g2     = (const float*)d_in[6];
    const float* Wout      = (const float*)d_in[7];
    const float* bn_out    = (const float*)d_in[8];
    const int*   idx_s1    = (const int*)d_in[9];
    const int*   idx_s2    = (const int*)d_in[10];
    float* out = (float*)d_out;

    if (ws_size >= WS_NEED) {
        _Float16* H1  = (_Float16*)d_ws;
        _Float16* H2  = (_Float16*)((char*)d_ws + H2_OFF);
        half8*    wof = (half8*)((char*)d_ws + WOF_OFF);
        float2*   sto = (float2*)((char*)d_ws + STO_OFF);
        prep_all<<<NB1 + NB2 + 1, 256, 0, stream>>>(
            feat_s1, feat_s2, Wg1, bn_g1, Wg2, bn_g2, Wout, bn_out,
            H1, H2, wof, sto);
        bignn_gather<<<(N_TILES + 3) / 4, 256, 0, stream>>>(
            H1, H2, feat_last, idx_s1, idx_s2, wof, sto, out);
    } else {
        bignn_ref<<<N_ROWS, 256, 0, stream>>>(
            feat_s1, feat_s2, feat_last, Wg1, bn_g1, Wg2, bn_g2, Wout, bn_out,
            idx_s1, idx_s2, out);
    }
}

// Round 11
// 58.211 us; speedup vs baseline: 1.2327x; 1.1473x over previous
//
#include <hip/hip_runtime.h>

// BiGNN R11: gather volume reduction. T1 gathered RAW (64B/row, half of H1's
// 128B) with grouper1 MLP inline: per neighbor-slot k, 4 MFMAs (M=16 targets)
// with sign-folded W1 so maxpool is elementwise f32 vmax on accumulators.
// T2 same pattern (raw=128B, volume-neutral vs H2 but prep shrinks to a pure
// cvt). p1/p2 transpose via wave-private LDS (f32, stride 132, 2-way only).
// Forced 8-slot load pipeline (R10) retained for both tables.

typedef __attribute__((ext_vector_type(8))) _Float16 half8;
typedef __attribute__((ext_vector_type(4))) int i32x4;
typedef __attribute__((ext_vector_type(4))) float f32x4;
typedef __attribute__((ext_vector_type(2))) _Float16 h2;

constexpr int N_ROWS = 50000;
constexpr int M1 = 200000, M2 = 100000;
constexpr int C1 = 32, C2 = 64, CL = 64, CG = 64;
constexpr float EPS = 1e-3f;
constexpr int N_TILES = N_ROWS / 16;                 // 3125

// ---- workspace layout (bytes) ----
constexpr size_t T1F_OFF = 0;                        // [M1][32] f16 = 12.8 MB
constexpr size_t T2F_OFF = (size_t)M1 * C1 * 2;      // [M2][64] f16 = 12.8 MB
constexpr size_t W1F_OFF = T2F_OFF + (size_t)M2 * C2 * 2;
constexpr size_t W2F_OFF = W1F_OFF + 4 * 64 * 16;
constexpr size_t WOF_OFF = W2F_OFF + 8 * 64 * 16;
constexpr size_t ST_OFF  = WOF_OFF + 24 * 64 * 16;
constexpr size_t WS_NEED = ST_OFF + 192 * 8;

__device__ __forceinline__ h2 pkrtz(float a, float b) {
    return (h2)__builtin_amdgcn_cvt_pkrtz(a, b);
}
__device__ __forceinline__ half8 pack8f(f32x4 x, f32x4 y) {
    h2 a = pkrtz(x[0], x[1]), b = pkrtz(x[2], x[3]);
    h2 c = pkrtz(y[0], y[1]), d = pkrtz(y[2], y[3]);
    half8 r;
    r[0]=a[0]; r[1]=a[1]; r[2]=b[0]; r[3]=b[1];
    r[4]=c[0]; r[5]=c[1]; r[6]=d[0]; r[7]=d[1];
    return r;
}
__device__ __forceinline__ f32x4 vmax4(f32x4 a, f32x4 b) {
    f32x4 r;
    r[0]=fmaxf(a[0],b[0]); r[1]=fmaxf(a[1],b[1]);
    r[2]=fmaxf(a[2],b[2]); r[3]=fmaxf(a[3],b[3]);
    return r;
}
#define MFMA16(a, b, c) __builtin_amdgcn_mfma_f32_16x16x32_f16((a), (b), (c), 0, 0, 0)
#define SBAR() __builtin_amdgcn_sched_barrier(0)
#define BC(x) __builtin_bit_cast(half8, x)

// ---- cvt: both tables f32 -> f16 ----
__global__ __launch_bounds__(256)
void cvt_f16(const float* __restrict__ s1, _Float16* __restrict__ d1, int n1_8,
             const float* __restrict__ s2, _Float16* __restrict__ d2, int n2_8) {
    for (int i = blockIdx.x * blockDim.x + threadIdx.x; i < n1_8 + n2_8;
         i += gridDim.x * blockDim.x) {
        const float* src = i < n1_8 ? s1 + (size_t)i * 8 : s2 + (size_t)(i - n1_8) * 8;
        _Float16* dst = i < n1_8 ? d1 + (size_t)i * 8 : d2 + (size_t)(i - n1_8) * 8;
        const f32x4* p = (const f32x4*)src;
        *(half8*)dst = pack8f(p[0], p[1]);
    }
}

// ---- weight frags (+BN consts): W1/W2 sign-folded, Wout plain ----
__global__ __launch_bounds__(256)
void prep_w(const float* __restrict__ Wg1, const float* __restrict__ Wg2,
            const float* __restrict__ Wout,
            const float* __restrict__ bn_g1, const float* __restrict__ bn_g2,
            const float* __restrict__ bn_out,
            half8* __restrict__ w1f, half8* __restrict__ w2f,
            half8* __restrict__ wof, float2* __restrict__ st) {
    int g = blockIdx.x * 256 + threadIdx.x;
    if (g < 4 * 64) {                                  // W1 frags [nt]
        int nt = g >> 6, lane = g & 63, lc = lane & 15, hi = lane >> 4;
        int d = nt * 16 + lc;
        float s = bn_g1[d] * rsqrtf(bn_g1[192 + d] + EPS);
        float sg = s >= 0.f ? 1.f : -1.f;
        half8 r;
#pragma unroll
        for (int j = 0; j < 8; ++j)
            r[j] = (_Float16)(Wg1[(hi * 8 + j) * CG + d] * sg);
        w1f[g] = r;
    } else if (g < 4 * 64 + 8 * 64) {                  // W2 frags [kk*4+nt]
        int gg = g - 256, fid = gg >> 6, lane = gg & 63;
        int kk = fid >> 2, nt = fid & 3, lc = lane & 15, hi = lane >> 4;
        int d = nt * 16 + lc;
        float s = bn_g2[d] * rsqrtf(bn_g2[192 + d] + EPS);
        float sg = s >= 0.f ? 1.f : -1.f;
        half8 r;
#pragma unroll
        for (int j = 0; j < 8; ++j)
            r[j] = (_Float16)(Wg2[(kk * 32 + hi * 8 + j) * CG + d] * sg);
        w2f[gg] = r;
    } else if (g < 36 * 64) {                          // Wout frags [ck*4+nt]
        int gg = g - 768, fid = gg >> 6, lane = gg & 63;
        int ck = fid >> 2, nt = fid & 3, lc = lane & 15, hi = lane >> 4;
        half8 r;
#pragma unroll
        for (int j = 0; j < 8; ++j)
            r[j] = (_Float16)Wout[(ck * 32 + hi * 8 + j) * CG + nt * 16 + lc];
        wof[gg] = r;
    } else if (g < 36 * 64 + 192) {                    // BN consts
        int i = g - 36 * 64, which = i >> 6, ch = i & 63;
        const float* bnp = which == 0 ? bn_g1 : which == 1 ? bn_g2 : bn_out;
        float s = bnp[ch] * rsqrtf(bnp[192 + ch] + EPS);
        float tt = fmaf(-bnp[128 + ch], s, bnp[64 + ch]);
        st[i] = make_float2(which == 2 ? s : fabsf(s), tt);
    }
}

// issue T1 raw row (64B covered by the 4 hi-groups, 16B/lane)
#define ISS1(S, ix) { S = *(const i32x4*)(const void*)(T1f + (size_t)(unsigned)(ix) * C1 + hi * 8); }
// issue T2 raw row (128B: two 16B chunks/lane)
#define ISS2(Sa, Sb, ix) { const _Float16* p_ = T2f + (size_t)(unsigned)(ix) * C2 + hi * 8; \
    Sa = *(const i32x4*)(const void*)p_; Sb = *(const i32x4*)(const void*)(p_ + 32); }
// grouper1 consume: 4 MFMA (zero C) + elementwise max
#define C1FIRST(G) { f32x4 z = {0,0,0,0}; half8 a_ = BC(G); \
    pm10 = MFMA16(a_, w1_0, z); pm11 = MFMA16(a_, w1_1, z); \
    pm12 = MFMA16(a_, w1_2, z); pm13 = MFMA16(a_, w1_3, z); }
#define C1STEP(G) { f32x4 z = {0,0,0,0}; half8 a_ = BC(G); \
    pm10 = vmax4(pm10, MFMA16(a_, w1_0, z)); \
    pm11 = vmax4(pm11, MFMA16(a_, w1_1, z)); \
    pm12 = vmax4(pm12, MFMA16(a_, w1_2, z)); \
    pm13 = vmax4(pm13, MFMA16(a_, w1_3, z)); }
// grouper2 consume: K=64 via chained pair of MFMAs per nt
#define C2FIRST(Sa, Sb) { f32x4 z = {0,0,0,0}; half8 a_ = BC(Sa), b_ = BC(Sb); \
    pm20 = MFMA16(b_, w2_10, MFMA16(a_, w2_00, z)); \
    pm21 = MFMA16(b_, w2_11, MFMA16(a_, w2_01, z)); \
    pm22 = MFMA16(b_, w2_12, MFMA16(a_, w2_02, z)); \
    pm23 = MFMA16(b_, w2_13, MFMA16(a_, w2_03, z)); }
#define C2STEP(Sa, Sb) { f32x4 z = {0,0,0,0}; half8 a_ = BC(Sa), b_ = BC(Sb); \
    pm20 = vmax4(pm20, MFMA16(b_, w2_10, MFMA16(a_, w2_00, z))); \
    pm21 = vmax4(pm21, MFMA16(b_, w2_11, MFMA16(a_, w2_01, z))); \
    pm22 = vmax4(pm22, MFMA16(b_, w2_12, MFMA16(a_, w2_02, z))); \
    pm23 = vmax4(pm23, MFMA16(b_, w2_13, MFMA16(a_, w2_03, z))); }
// p finish: relu(|s|*pm + t) -> LDS  (target = hi*4+j, ch = cb+lc)
#define PSTORE(pm, sg, cb) { \
    Pw[(hi * 4 + 0) * 132 + (cb) + lc] = fmaxf(0.f, fmaf(sg.x, pm[0], sg.y)); \
    Pw[(hi * 4 + 1) * 132 + (cb) + lc] = fmaxf(0.f, fmaf(sg.x, pm[1], sg.y)); \
    Pw[(hi * 4 + 2) * 132 + (cb) + lc] = fmaxf(0.f, fmaf(sg.x, pm[2], sg.y)); \
    Pw[(hi * 4 + 3) * 132 + (cb) + lc] = fmaxf(0.f, fmaf(sg.x, pm[3], sg.y)); }

__global__ __launch_bounds__(256, 3)
void bignn_fused(const _Float16* __restrict__ T1f, const _Float16* __restrict__ T2f,
                 const float* __restrict__ feat_last,
                 const int* __restrict__ idx1, const int* __restrict__ idx2,
                 const half8* __restrict__ w1f, const half8* __restrict__ w2f,
                 const half8* __restrict__ wof, const float2* __restrict__ st,
                 float* __restrict__ out)
{
    __shared__ float P[4][16][132];                   // wave-private p1|p2 (f32)

    const int t = threadIdx.x, lane = t & 63, lc = lane & 15, hi = lane >> 4;
    const int wave = t >> 6;
    const int tile = blockIdx.x * 4 + wave;
    if (tile >= N_TILES) return;                      // no barriers in kernel
    const int row = tile * 16 + lc;
    float* Pw = &P[wave][0][0];

    // ---- T1: indices + fill 8 slots (8 x 16B in flight) ----
    const int* ip1 = idx1 + (size_t)row * 16;
    i32x4 I1a = *(const i32x4*)(const void*)(ip1);
    i32x4 I1b = *(const i32x4*)(const void*)(ip1 + 4);
    i32x4 I1c = *(const i32x4*)(const void*)(ip1 + 8);
    i32x4 I1d = *(const i32x4*)(const void*)(ip1 + 12);
    i32x4 G0, G1, G2, G3, G4, G5, G6, G7;
    ISS1(G0, I1a[0]); ISS1(G1, I1a[1]); ISS1(G2, I1a[2]); ISS1(G3, I1a[3]);
    ISS1(G4, I1b[0]); ISS1(G5, I1b[1]); ISS1(G6, I1b[2]); ISS1(G7, I1b[3]);
    SBAR();

    const int* ip2 = idx2 + (size_t)row * 16;
    i32x4 I2a = *(const i32x4*)(const void*)(ip2);
    i32x4 I2b = *(const i32x4*)(const void*)(ip2 + 4);
    i32x4 I2c = *(const i32x4*)(const void*)(ip2 + 8);
    i32x4 I2d = *(const i32x4*)(const void*)(ip2 + 12);

    half8 w1_0 = w1f[lane], w1_1 = w1f[64 + lane];
    half8 w1_2 = w1f[128 + lane], w1_3 = w1f[192 + lane];
    float2 sg10 = st[lc], sg11 = st[16 + lc], sg12 = st[32 + lc], sg13 = st[48 + lc];
    SBAR();

    f32x4 pm10, pm11, pm12, pm13;
    C1FIRST(G0); ISS1(G0, I1c[0]); SBAR();
    C1STEP(G1);  ISS1(G1, I1c[1]); SBAR();
    C1STEP(G2);  ISS1(G2, I1c[2]); SBAR();
    C1STEP(G3);  ISS1(G3, I1c[3]); SBAR();
    C1STEP(G4);  ISS1(G4, I1d[0]); SBAR();
    C1STEP(G5);  ISS1(G5, I1d[1]); SBAR();
    C1STEP(G6);  ISS1(G6, I1d[2]); SBAR();
    C1STEP(G7);  ISS1(G7, I1d[3]); SBAR();

    // T1 drain; T2 slots issue underneath
    i32x4 S0a, S0b, S1a, S1b, S2a, S2b, S3a, S3b;
    i32x4 S4a, S4b, S5a, S5b, S6a, S6b, S7a, S7b;
    C1STEP(G0); ISS2(S0a, S0b, I2a[0]); SBAR();
    C1STEP(G1); ISS2(S1a, S1b, I2a[1]); SBAR();
    C1STEP(G2); ISS2(S2a, S2b, I2a[2]); SBAR();
    C1STEP(G3); ISS2(S3a, S3b, I2a[3]); SBAR();
    C1STEP(G4); ISS2(S4a, S4b, I2b[0]); SBAR();
    C1STEP(G5); ISS2(S5a, S5b, I2b[1]); SBAR();
    C1STEP(G6); ISS2(S6a, S6b, I2b[2]); SBAR();
    C1STEP(G7); ISS2(S7a, S7b, I2b[3]); SBAR();

    PSTORE(pm10, sg10, 0); PSTORE(pm11, sg11, 16);
    PSTORE(pm12, sg12, 32); PSTORE(pm13, sg13, 48);

    // ---- T2 phase ----
    half8 w2_00 = w2f[lane],        w2_01 = w2f[64 + lane];
    half8 w2_02 = w2f[128 + lane],  w2_03 = w2f[192 + lane];
    half8 w2_10 = w2f[256 + lane],  w2_11 = w2f[320 + lane];
    half8 w2_12 = w2f[384 + lane],  w2_13 = w2f[448 + lane];
    float2 sg20 = st[64 + lc], sg21 = st[80 + lc];
    float2 sg22 = st[96 + lc], sg23 = st[112 + lc];

    f32x4 pm20, pm21, pm22, pm23;
    C2FIRST(S0a, S0b); ISS2(S0a, S0b, I2c[0]); SBAR();
    C2STEP(S1a, S1b);  ISS2(S1a, S1b, I2c[1]); SBAR();
    C2STEP(S2a, S2b);  ISS2(S2a, S2b, I2c[2]); SBAR();
    C2STEP(S3a, S3b);  ISS2(S3a, S3b, I2c[3]); SBAR();
    C2STEP(S4a, S4b);  ISS2(S4a, S4b, I2d[0]); SBAR();
    C2STEP(S5a, S5b);  ISS2(S5a, S5b, I2d[1]); SBAR();
    C2STEP(S6a, S6b);  ISS2(S6a, S6b, I2d[2]); SBAR();
    C2STEP(S7a, S7b);  ISS2(S7a, S7b, I2d[3]); SBAR();
    C2STEP(S0a, S0b); SBAR();
    C2STEP(S1a, S1b); SBAR();
    // feat_last under the drain
    const f32x4* flp = (const f32x4*)(feat_last + (size_t)row * CL + hi * 8);
    f32x4 f0 = flp[0], f1 = flp[1];
    const f32x4* flq = (const f32x4*)(feat_last + (size_t)row * CL + 32 + hi * 8);
    f32x4 f2 = flq[0], f3 = flq[1];
    SBAR();
    C2STEP(S2a, S2b); SBAR();
    C2STEP(S3a, S3b); SBAR();
    C2STEP(S4a, S4b); SBAR();
    C2STEP(S5a, S5b); SBAR();
    C2STEP(S6a, S6b); SBAR();
    C2STEP(S7a, S7b);

    PSTORE(pm20, sg20, 64); PSTORE(pm21, sg21, 80);
    PSTORE(pm22, sg22, 96); PSTORE(pm23, sg23, 112);

    // ---- final layer: A = [feat_last | p1 | p2] via LDS transpose ----
    half8 A0 = pack8f(f0, f1), A1 = pack8f(f2, f3);
    f32x4 facc0 = {0,0,0,0}, facc1 = {0,0,0,0}, facc2 = {0,0,0,0}, facc3 = {0,0,0,0};
#pragma unroll
    for (int ck = 0; ck < 6; ++ck) {
        half8 B;
        if (ck == 0) B = A0;
        else if (ck == 1) B = A1;
        else {
            const f32x4* pp = (const f32x4*)(const void*)(Pw + lc * 132 + (ck - 2) * 32 + hi * 8);
            B = pack8f(pp[0], pp[1]);
        }
        facc0 = MFMA16(wof[(ck * 4 + 0) * 64 + lane], B, facc0);
        facc1 = MFMA16(wof[(ck * 4 + 1) * 64 + lane], B, facc1);
        facc2 = MFMA16(wof[(ck * 4 + 2) * 64 + lane], B, facc2);
        facc3 = MFMA16(wof[(ck * 4 + 3) * 64 + lane], B, facc3);
    }

    const float* stf = (const float*)(st + 128);
    f32x4 fa[4] = {facc0, facc1, facc2, facc3};
#pragma unroll
    for (int nt = 0; nt < 4; ++nt) {
        const int ch = nt * 16 + hi * 4;
        f32x4 s01 = *(const f32x4*)(stf + ch * 2);      // s0 t0 s1 t1
        f32x4 s23 = *(const f32x4*)(stf + ch * 2 + 4);  // s2 t2 s3 t3
        f32x4 v;
        v[0] = fmaxf(0.f, fmaf(s01[0], fa[nt][0], s01[1]));
        v[1] = fmaxf(0.f, fmaf(s01[2], fa[nt][1], s01[3]));
        v[2] = fmaxf(0.f, fmaf(s23[0], fa[nt][2], s23[1]));
        v[3] = fmaxf(0.f, fmaf(s23[2], fa[nt][3], s23[3]));
        *(f32x4*)(out + (size_t)row * CG + ch) = v;
    }
}

// ---- fallback (ws too small): one block per row, f32, correct but slow ----
__global__ __launch_bounds__(256)
void bignn_ref(const float* __restrict__ feat_s1, const float* __restrict__ feat_s2,
               const float* __restrict__ feat_last,
               const float* __restrict__ Wg1, const float* __restrict__ bn_g1,
               const float* __restrict__ Wg2, const float* __restrict__ bn_g2,
               const float* __restrict__ Wout, const float* __restrict__ bn_out,
               const int* __restrict__ idx_s1, const int* __restrict__ idx_s2,
               float* __restrict__ out)
{
    __shared__ float p[128];
    const int row = blockIdx.x, t = threadIdx.x;
    if (t < 128) {
        const int ch = t & 63;
        const bool g2 = t >= 64;
        const float* bn = g2 ? bn_g2 : bn_g1;
        const float* W  = g2 ? Wg2 : Wg1;
        const float* tab = g2 ? feat_s2 : feat_s1;
        const int*   idx = g2 ? idx_s2 : idx_s1;
        const int C = g2 ? C2 : C1;
        float s = bn[ch] * rsqrtf(bn[192 + ch] + EPS);
        float tt = fmaf(-bn[128 + ch], s, bn[64 + ch]);
        float pv = 0.f;
        for (int k = 0; k < 16; ++k) {
            int nb = idx[(size_t)row * 16 + k];
            float h = 0.f;
            for (int c = 0; c < C; ++c)
                h = fmaf(tab[(size_t)nb * C + c], W[c * CG + ch], h);
            pv = fmaxf(pv, fmaxf(0.f, fmaf(s, h, tt)));
        }
        p[t] = pv;
    }
    __syncthreads();
    if (t < 64) {
        float acc = 0.f;
        for (int j = 0; j < 64; ++j)
            acc = fmaf(feat_last[(size_t)row * CL + j], Wout[j * CG + t], acc);
        for (int j = 0; j < 128; ++j)
            acc = fmaf(p[j], Wout[(64 + j) * CG + t], acc);
        float s = bn_out[t] * rsqrtf(bn_out[192 + t] + EPS);
        float tt = fmaf(-bn_out[128 + t], s, bn_out[64 + t]);
        out[(size_t)row * CG + t] = fmaxf(0.f, fmaf(s, acc, tt));
    }
}

extern "C" void kernel_launch(void* const* d_in, const int* in_sizes, int n_in,
                              void* d_out, int out_size, void* d_ws, size_t ws_size,
                              hipStream_t stream) {
    const float* feat_s1   = (const float*)d_in[0];
    const float* feat_s2   = (const float*)d_in[1];
    const float* feat_last = (const float*)d_in[2];
    const float* Wg1       = (const float*)d_in[3];
    const float* bn_g1     = (const float*)d_in[4];
    const float* Wg2       = (const float*)d_in[5];
    const float* bn_g2     = (const float*)d_in[6];
    const float* Wout      = (const float*)d_in[7];
    const float* bn_out    = (const float*)d_in[8];
    const int*   idx_s1    = (const int*)d_in[9];
    const int*   idx_s2    = (const int*)d_in[10];
    float* out = (float*)d_out;

    if (ws_size >= WS_NEED) {
        _Float16* T1f = (_Float16*)((char*)d_ws + T1F_OFF);
        _Float16* T2f = (_Float16*)((char*)d_ws + T2F_OFF);
        half8* w1f = (half8*)((char*)d_ws + W1F_OFF);
        half8* w2f = (half8*)((char*)d_ws + W2F_OFF);
        half8* wof = (half8*)((char*)d_ws + WOF_OFF);
        float2* st = (float2*)((char*)d_ws + ST_OFF);
        cvt_f16<<<2048, 256, 0, stream>>>(feat_s1, T1f, (int)((size_t)M1 * C1 / 8),
                                          feat_s2, T2f, (int)((size_t)M2 * C2 / 8));
        prep_w<<<10, 256, 0, stream>>>(Wg1, Wg2, Wout, bn_g1, bn_g2, bn_out,
                                       w1f, w2f, wof, st);
        bignn_fused<<<(N_TILES + 3) / 4, 256, 0, stream>>>(
            T1f, T2f, feat_last, idx_s1, idx_s2, w1f, w2f, wof, st, out);
    } else {
        bignn_ref<<<N_ROWS, 256, 0, stream>>>(
            feat_s1, feat_s2, feat_last, Wg1, bn_g1, Wg2, bn_g2, Wout, bn_out,
            idx_s1, idx_s2, out);
    }
}

// Round 12
// 56.589 us; speedup vs baseline: 1.2681x; 1.0287x over previous
//
#include <hip/hip_runtime.h>

// BiGNN R12: R11 volume (raw-f16 T1 64B + raw T2 128B, inline sign-folded
// MFMA groupers) + FULL 16-instr load depth the whole kernel: T1's 16 rows
// prologue-issued into 8 double-slots; each phase-A step consumes 2 T1 rows
// and refills with a T2 row; phase-B steady 16 T2 instr. cvt+prep merged.

typedef __attribute__((ext_vector_type(8))) _Float16 half8;
typedef __attribute__((ext_vector_type(4))) int i32x4;
typedef __attribute__((ext_vector_type(4))) float f32x4;
typedef __attribute__((ext_vector_type(2))) _Float16 h2;

constexpr int N_ROWS = 50000;
constexpr int M1 = 200000, M2 = 100000;
constexpr int C1 = 32, C2 = 64, CL = 64, CG = 64;
constexpr float EPS = 1e-3f;
constexpr int N_TILES = N_ROWS / 16;                 // 3125

// ---- workspace layout (bytes) ----
constexpr size_t T1F_OFF = 0;                        // [M1][32] f16
constexpr size_t T2F_OFF = (size_t)M1 * C1 * 2;      // [M2][64] f16
constexpr size_t W1F_OFF = T2F_OFF + (size_t)M2 * C2 * 2;
constexpr size_t W2F_OFF = W1F_OFF + 4 * 64 * 16;
constexpr size_t WOF_OFF = W2F_OFF + 8 * 64 * 16;
constexpr size_t ST_OFF  = WOF_OFF + 24 * 64 * 16;
constexpr size_t WS_NEED = ST_OFF + 192 * 8;

constexpr int CVT_BLKS = 2048;

__device__ __forceinline__ h2 pkrtz(float a, float b) {
    return (h2)__builtin_amdgcn_cvt_pkrtz(a, b);
}
__device__ __forceinline__ half8 pack8f(f32x4 x, f32x4 y) {
    h2 a = pkrtz(x[0], x[1]), b = pkrtz(x[2], x[3]);
    h2 c = pkrtz(y[0], y[1]), d = pkrtz(y[2], y[3]);
    half8 r;
    r[0]=a[0]; r[1]=a[1]; r[2]=b[0]; r[3]=b[1];
    r[4]=c[0]; r[5]=c[1]; r[6]=d[0]; r[7]=d[1];
    return r;
}
__device__ __forceinline__ f32x4 vmax4(f32x4 a, f32x4 b) {
    f32x4 r;
    r[0]=fmaxf(a[0],b[0]); r[1]=fmaxf(a[1],b[1]);
    r[2]=fmaxf(a[2],b[2]); r[3]=fmaxf(a[3],b[3]);
    return r;
}
#define MFMA16(a, b, c) __builtin_amdgcn_mfma_f32_16x16x32_f16((a), (b), (c), 0, 0, 0)
#define SBAR() __builtin_amdgcn_sched_barrier(0)
#define BC(x) __builtin_bit_cast(half8, x)

// ---- merged prep: table cvt (blocks < CVT_BLKS) | weight frags + BN ----
__global__ __launch_bounds__(256)
void prep_all(const float* __restrict__ fs1, const float* __restrict__ fs2,
              const float* __restrict__ Wg1, const float* __restrict__ Wg2,
              const float* __restrict__ Wout,
              const float* __restrict__ bn_g1, const float* __restrict__ bn_g2,
              const float* __restrict__ bn_out,
              _Float16* __restrict__ T1f, _Float16* __restrict__ T2f,
              half8* __restrict__ w1f, half8* __restrict__ w2f,
              half8* __restrict__ wof, float2* __restrict__ st)
{
    if (blockIdx.x < CVT_BLKS) {
        const int n1_8 = (int)((size_t)M1 * C1 / 8);
        const int n2_8 = (int)((size_t)M2 * C2 / 8);
        for (int i = blockIdx.x * 256 + threadIdx.x; i < n1_8 + n2_8;
             i += CVT_BLKS * 256) {
            const float* src = i < n1_8 ? fs1 + (size_t)i * 8 : fs2 + (size_t)(i - n1_8) * 8;
            _Float16* dst = i < n1_8 ? T1f + (size_t)i * 8 : T2f + (size_t)(i - n1_8) * 8;
            const f32x4* p = (const f32x4*)src;
            *(half8*)dst = pack8f(p[0], p[1]);
        }
        return;
    }
    int g = (blockIdx.x - CVT_BLKS) * 256 + threadIdx.x;
    if (g < 4 * 64) {                                  // W1 frags (sign-folded)
        int nt = g >> 6, lane = g & 63, lc = lane & 15, hi = lane >> 4;
        int d = nt * 16 + lc;
        float s = bn_g1[d] * rsqrtf(bn_g1[192 + d] + EPS);
        float sg = s >= 0.f ? 1.f : -1.f;
        half8 r;
#pragma unroll
        for (int j = 0; j < 8; ++j)
            r[j] = (_Float16)(Wg1[(hi * 8 + j) * CG + d] * sg);
        w1f[g] = r;
    } else if (g < 4 * 64 + 8 * 64) {                  // W2 frags (sign-folded)
        int gg = g - 256, fid = gg >> 6, lane = gg & 63;
        int kk = fid >> 2, nt = fid & 3, lc = lane & 15, hi = lane >> 4;
        int d = nt * 16 + lc;
        float s = bn_g2[d] * rsqrtf(bn_g2[192 + d] + EPS);
        float sg = s >= 0.f ? 1.f : -1.f;
        half8 r;
#pragma unroll
        for (int j = 0; j < 8; ++j)
            r[j] = (_Float16)(Wg2[(kk * 32 + hi * 8 + j) * CG + d] * sg);
        w2f[gg] = r;
    } else if (g < 36 * 64) {                          // Wout frags
        int gg = g - 768, fid = gg >> 6, lane = gg & 63;
        int ck = fid >> 2, nt = fid & 3, lc = lane & 15, hi = lane >> 4;
        half8 r;
#pragma unroll
        for (int j = 0; j < 8; ++j)
            r[j] = (_Float16)Wout[(ck * 32 + hi * 8 + j) * CG + nt * 16 + lc];
        wof[gg] = r;
    } else if (g < 36 * 64 + 192) {                    // BN consts
        int i = g - 36 * 64, which = i >> 6, ch = i & 63;
        const float* bnp = which == 0 ? bn_g1 : which == 1 ? bn_g2 : bn_out;
        float s = bnp[ch] * rsqrtf(bnp[192 + ch] + EPS);
        float tt = fmaf(-bnp[128 + ch], s, bnp[64 + ch]);
        st[i] = make_float2(which == 2 ? s : fabsf(s), tt);
    }
}

// issue T1 raw row (16B/lane) into one half-slot register
#define ISS1(R, ix) { R = *(const i32x4*)(const void*)(T1f + (size_t)(unsigned)(ix) * C1 + hi * 8); }
// issue T2 raw row (2 x 16B/lane) into a full slot (x,y)
#define ISS2(Sx, Sy, ix) { const _Float16* p_ = T2f + (size_t)(unsigned)(ix) * C2 + hi * 8; \
    Sx = *(const i32x4*)(const void*)p_; Sy = *(const i32x4*)(const void*)(p_ + 32); }
// grouper1 consume one row-reg
#define C1F(R) { f32x4 z = {0,0,0,0}; half8 a_ = BC(R); \
    pm10 = MFMA16(a_, w1_0, z); pm11 = MFMA16(a_, w1_1, z); \
    pm12 = MFMA16(a_, w1_2, z); pm13 = MFMA16(a_, w1_3, z); }
#define C1S(R) { f32x4 z = {0,0,0,0}; half8 a_ = BC(R); \
    pm10 = vmax4(pm10, MFMA16(a_, w1_0, z)); \
    pm11 = vmax4(pm11, MFMA16(a_, w1_1, z)); \
    pm12 = vmax4(pm12, MFMA16(a_, w1_2, z)); \
    pm13 = vmax4(pm13, MFMA16(a_, w1_3, z)); }
// grouper2 consume one slot (K=64 chained pairs)
#define C2F(Sx, Sy) { f32x4 z = {0,0,0,0}; half8 a_ = BC(Sx), b_ = BC(Sy); \
    pm20 = MFMA16(b_, w2_10, MFMA16(a_, w2_00, z)); \
    pm21 = MFMA16(b_, w2_11, MFMA16(a_, w2_01, z)); \
    pm22 = MFMA16(b_, w2_12, MFMA16(a_, w2_02, z)); \
    pm23 = MFMA16(b_, w2_13, MFMA16(a_, w2_03, z)); }
#define C2S(Sx, Sy) { f32x4 z = {0,0,0,0}; half8 a_ = BC(Sx), b_ = BC(Sy); \
    pm20 = vmax4(pm20, MFMA16(b_, w2_10, MFMA16(a_, w2_00, z))); \
    pm21 = vmax4(pm21, MFMA16(b_, w2_11, MFMA16(a_, w2_01, z))); \
    pm22 = vmax4(pm22, MFMA16(b_, w2_12, MFMA16(a_, w2_02, z))); \
    pm23 = vmax4(pm23, MFMA16(b_, w2_13, MFMA16(a_, w2_03, z))); }
// p finish: relu(|s|*pm + t) -> LDS  (target row = hi*4+j, channel = cb+lc)
#define PSTORE(pm, sg, cb) { \
    Pw[(hi * 4 + 0) * 132 + (cb) + lc] = fmaxf(0.f, fmaf(sg.x, pm[0], sg.y)); \
    Pw[(hi * 4 + 1) * 132 + (cb) + lc] = fmaxf(0.f, fmaf(sg.x, pm[1], sg.y)); \
    Pw[(hi * 4 + 2) * 132 + (cb) + lc] = fmaxf(0.f, fmaf(sg.x, pm[2], sg.y)); \
    Pw[(hi * 4 + 3) * 132 + (cb) + lc] = fmaxf(0.f, fmaf(sg.x, pm[3], sg.y)); }

__global__ __launch_bounds__(256, 3)
void bignn_fused(const _Float16* __restrict__ T1f, const _Float16* __restrict__ T2f,
                 const float* __restrict__ feat_last,
                 const int* __restrict__ idx1, const int* __restrict__ idx2,
                 const half8* __restrict__ w1f, const half8* __restrict__ w2f,
                 const half8* __restrict__ wof, const float2* __restrict__ st,
                 float* __restrict__ out)
{
    __shared__ float P[4][16][132];                   // wave-private p1|p2 (f32)

    const int t = threadIdx.x, lane = t & 63, lc = lane & 15, hi = lane >> 4;
    const int wave = t >> 6;
    const int tile = blockIdx.x * 4 + wave;
    if (tile >= N_TILES) return;                      // no block barriers used
    const int row = tile * 16 + lc;
    float* Pw = &P[wave][0][0];

    // ---- T1 indices + prologue: ALL 16 T1 rows in flight (16 instr) ----
    const int* ip1 = idx1 + (size_t)row * 16;
    i32x4 I1a = *(const i32x4*)(const void*)(ip1);
    i32x4 I1b = *(const i32x4*)(const void*)(ip1 + 4);
    i32x4 I1c = *(const i32x4*)(const void*)(ip1 + 8);
    i32x4 I1d = *(const i32x4*)(const void*)(ip1 + 12);

    i32x4 S0x, S0y, S1x, S1y, S2x, S2y, S3x, S3y;
    i32x4 S4x, S4y, S5x, S5y, S6x, S6y, S7x, S7y;
    ISS1(S0x, I1a[0]); ISS1(S0y, I1a[1]);
    ISS1(S1x, I1a[2]); ISS1(S1y, I1a[3]);
    ISS1(S2x, I1b[0]); ISS1(S2y, I1b[1]);
    ISS1(S3x, I1b[2]); ISS1(S3y, I1b[3]);
    ISS1(S4x, I1c[0]); ISS1(S4y, I1c[1]);
    ISS1(S5x, I1c[2]); ISS1(S5y, I1c[3]);
    ISS1(S6x, I1d[0]); ISS1(S6y, I1d[1]);
    ISS1(S7x, I1d[2]); ISS1(S7y, I1d[3]);
    SBAR();

    const int* ip2 = idx2 + (size_t)row * 16;
    i32x4 I2a = *(const i32x4*)(const void*)(ip2);
    i32x4 I2b = *(const i32x4*)(const void*)(ip2 + 4);
    i32x4 I2c = *(const i32x4*)(const void*)(ip2 + 8);
    i32x4 I2d = *(const i32x4*)(const void*)(ip2 + 12);

    half8 w1_0 = w1f[lane], w1_1 = w1f[64 + lane];
    half8 w1_2 = w1f[128 + lane], w1_3 = w1f[192 + lane];
    float2 sg10 = st[lc], sg11 = st[16 + lc], sg12 = st[32 + lc], sg13 = st[48 + lc];
    SBAR();

    // ---- phase A: consume 2 T1 rows/step, refill slot with a T2 row ----
    f32x4 pm10, pm11, pm12, pm13;
    C1F(S0x); C1S(S0y); ISS2(S0x, S0y, I2a[0]); SBAR();
    C1S(S1x); C1S(S1y); ISS2(S1x, S1y, I2a[1]); SBAR();
    C1S(S2x); C1S(S2y); ISS2(S2x, S2y, I2a[2]); SBAR();
    C1S(S3x); C1S(S3y); ISS2(S3x, S3y, I2a[3]); SBAR();
    // w2 frags fetched here (L2-hot); arrive before phase B needs them
    half8 w2_00 = w2f[lane],        w2_01 = w2f[64 + lane];
    half8 w2_02 = w2f[128 + lane],  w2_03 = w2f[192 + lane];
    half8 w2_10 = w2f[256 + lane],  w2_11 = w2f[320 + lane];
    half8 w2_12 = w2f[384 + lane],  w2_13 = w2f[448 + lane];
    SBAR();
    C1S(S4x); C1S(S4y); ISS2(S4x, S4y, I2b[0]); SBAR();
    C1S(S5x); C1S(S5y); ISS2(S5x, S5y, I2b[1]); SBAR();
    C1S(S6x); C1S(S6y); ISS2(S6x, S6y, I2b[2]); SBAR();
    C1S(S7x); C1S(S7y); ISS2(S7x, S7y, I2b[3]); SBAR();

    PSTORE(pm10, sg10, 0); PSTORE(pm11, sg11, 16);
    PSTORE(pm12, sg12, 32); PSTORE(pm13, sg13, 48);
    float2 sg20 = st[64 + lc], sg21 = st[80 + lc];
    float2 sg22 = st[96 + lc], sg23 = st[112 + lc];

    // ---- phase B: steady 16 T2 instr in flight ----
    f32x4 pm20, pm21, pm22, pm23;
    C2F(S0x, S0y); ISS2(S0x, S0y, I2c[0]); SBAR();
    C2S(S1x, S1y); ISS2(S1x, S1y, I2c[1]); SBAR();
    C2S(S2x, S2y); ISS2(S2x, S2y, I2c[2]); SBAR();
    C2S(S3x, S3y); ISS2(S3x, S3y, I2c[3]); SBAR();
    C2S(S4x, S4y); ISS2(S4x, S4y, I2d[0]); SBAR();
    C2S(S5x, S5y); ISS2(S5x, S5y, I2d[1]); SBAR();
    C2S(S6x, S6y); ISS2(S6x, S6y, I2d[2]); SBAR();
    C2S(S7x, S7y); ISS2(S7x, S7y, I2d[3]); SBAR();

    // ---- phase C: drain; feat_last loads overlap ----
    C2S(S0x, S0y); SBAR();
    C2S(S1x, S1y); SBAR();
    const f32x4* flp = (const f32x4*)(feat_last + (size_t)row * CL + hi * 8);
    f32x4 f0 = flp[0], f1 = flp[1];
    const f32x4* flq = (const f32x4*)(feat_last + (size_t)row * CL + 32 + hi * 8);
    f32x4 f2 = flq[0], f3 = flq[1];
    SBAR();
    C2S(S2x, S2y); SBAR();
    C2S(S3x, S3y); SBAR();
    C2S(S4x, S4y); SBAR();
    C2S(S5x, S5y); SBAR();
    C2S(S6x, S6y); SBAR();
    C2S(S7x, S7y);

    PSTORE(pm20, sg20, 64); PSTORE(pm21, sg21, 80);
    PSTORE(pm22, sg22, 96); PSTORE(pm23, sg23, 112);

    // ---- final layer: A = [feat_last | p1 | p2] via LDS transpose ----
    half8 A0 = pack8f(f0, f1), A1 = pack8f(f2, f3);
    f32x4 facc0 = {0,0,0,0}, facc1 = {0,0,0,0}, facc2 = {0,0,0,0}, facc3 = {0,0,0,0};
#pragma unroll
    for (int ck = 0; ck < 6; ++ck) {
        half8 B;
        if (ck == 0) B = A0;
        else if (ck == 1) B = A1;
        else {
            const f32x4* pp = (const f32x4*)(const void*)(Pw + lc * 132 + (ck - 2) * 32 + hi * 8);
            B = pack8f(pp[0], pp[1]);
        }
        facc0 = MFMA16(wof[(ck * 4 + 0) * 64 + lane], B, facc0);
        facc1 = MFMA16(wof[(ck * 4 + 1) * 64 + lane], B, facc1);
        facc2 = MFMA16(wof[(ck * 4 + 2) * 64 + lane], B, facc2);
        facc3 = MFMA16(wof[(ck * 4 + 3) * 64 + lane], B, facc3);
    }

    const float* stf = (const float*)(st + 128);
    f32x4 fa[4] = {facc0, facc1, facc2, facc3};
#pragma unroll
    for (int nt = 0; nt < 4; ++nt) {
        const int ch = nt * 16 + hi * 4;
        f32x4 s01 = *(const f32x4*)(stf + ch * 2);      // s0 t0 s1 t1
        f32x4 s23 = *(const f32x4*)(stf + ch * 2 + 4);  // s2 t2 s3 t3
        f32x4 v;
        v[0] = fmaxf(0.f, fmaf(s01[0], fa[nt][0], s01[1]));
        v[1] = fmaxf(0.f, fmaf(s01[2], fa[nt][1], s01[3]));
        v[2] = fmaxf(0.f, fmaf(s23[0], fa[nt][2], s23[1]));
        v[3] = fmaxf(0.f, fmaf(s23[2], fa[nt][3], s23[3]));
        *(f32x4*)(out + (size_t)row * CG + ch) = v;
    }
}

// ---- fallback (ws too small): one block per row, f32, correct but slow ----
__global__ __launch_bounds__(256)
void bignn_ref(const float* __restrict__ feat_s1, const float* __restrict__ feat_s2,
               const float* __restrict__ feat_last,
               const float* __restrict__ Wg1, const float* __restrict__ bn_g1,
               const float* __restrict__ Wg2, const float* __restrict__ bn_g2,
               const float* __restrict__ Wout, const float* __restrict__ bn_out,
               const int* __restrict__ idx_s1, const int* __restrict__ idx_s2,
               float* __restrict__ out)
{
    __shared__ float p[128];
    const int row = blockIdx.x, t = threadIdx.x;
    if (t < 128) {
        const int ch = t & 63;
        const bool g2 = t >= 64;
        const float* bn = g2 ? bn_g2 : bn_g1;
        const float* W  = g2 ? Wg2 : Wg1;
        const float* tab = g2 ? feat_s2 : feat_s1;
        const int*   idx = g2 ? idx_s2 : idx_s1;
        const int C = g2 ? C2 : C1;
        float s = bn[ch] * rsqrtf(bn[192 + ch] + EPS);
        float tt = fmaf(-bn[128 + ch], s, bn[64 + ch]);
        float pv = 0.f;
        for (int k = 0; k < 16; ++k) {
            int nb = idx[(size_t)row * 16 + k];
            float h = 0.f;
            for (int c = 0; c < C; ++c)
                h = fmaf(tab[(size_t)nb * C + c], W[c * CG + ch], h);
            pv = fmaxf(pv, fmaxf(0.f, fmaf(s, h, tt)));
        }
        p[t] = pv;
    }
    __syncthreads();
    if (t < 64) {
        float acc = 0.f;
        for (int j = 0; j < 64; ++j)
            acc = fmaf(feat_last[(size_t)row * CL + j], Wout[j * CG + t], acc);
        for (int j = 0; j < 128; ++j)
            acc = fmaf(p[j], Wout[(64 + j) * CG + t], acc);
        float s = bn_out[t] * rsqrtf(bn_out[192 + t] + EPS);
        float tt = fmaf(-bn_out[128 + t], s, bn_out[64 + t]);
        out[(size_t)row * CG + t] = fmaxf(0.f, fmaf(s, acc, tt));
    }
}

extern "C" void kernel_launch(void* const* d_in, const int* in_sizes, int n_in,
                              void* d_out, int out_size, void* d_ws, size_t ws_size,
                              hipStream_t stream) {
    const float* feat_s1   = (const float*)d_in[0];
    const float* feat_s2   = (const float*)d_in[1];
    const float* feat_last = (const float*)d_in[2];
    const float* Wg1       = (const float*)d_in[3];
    const float* bn_g1     = (const float*)d_in[4];
    const float* Wg2       = (const float*)d_in[5];
    const float* bn_g2     = (const float*)d_in[6];
    const float* Wout      = (const float*)d_in[7];
    const float* bn_out    = (const float*)d_in[8];
    const int*   idx_s1    = (const int*)d_in[9];
    const int*   idx_s2    = (const int*)d_in[10];
    float* out = (float*)d_out;

    if (ws_size >= WS_NEED) {
        _Float16* T1f = (_Float16*)((char*)d_ws + T1F_OFF);
        _Float16* T2f = (_Float16*)((char*)d_ws + T2F_OFF);
        half8* w1f = (half8*)((char*)d_ws + W1F_OFF);
        half8* w2f = (half8*)((char*)d_ws + W2F_OFF);
        half8* wof = (half8*)((char*)d_ws + WOF_OFF);
        float2* st = (float2*)((char*)d_ws + ST_OFF);
        prep_all<<<CVT_BLKS + 10, 256, 0, stream>>>(
            feat_s1, feat_s2, Wg1, Wg2, Wout, bn_g1, bn_g2, bn_out,
            T1f, T2f, w1f, w2f, wof, st);
        bignn_fused<<<(N_TILES + 3) / 4, 256, 0, stream>>>(
            T1f, T2f, feat_last, idx_s1, idx_s2, w1f, w2f, wof, st, out);
    } else {
        bignn_ref<<<N_ROWS, 256, 0, stream>>>(
            feat_s1, feat_s2, feat_last, Wg1, bn_g1, Wg2, bn_g2, Wout, bn_out,
            idx_s1, idx_s2, out);
    }
}